// Round 6
// baseline (181.496 us; speedup 1.0000x reference)
//
#include <hip/hip_runtime.h>

// GRU (B=4096, T=512, I=1, H=32) + FC(32->12), fused, pk_fma_f16 matvec.
//
// Layout (round-4 grid): lane = (batch, hidden unit j). 32 lanes per batch
// element, 2 per wave64, 8 per 256-thread block -> 2048 waves = 2/SIMD.
//
// Round 3/4/5 busy-cycle fits show v_dot2_f32_f16 is HALF-RATE (~4 cyc) on
// gfx950 - same FLOP rate as scalar fma. v_pk_fma_f16 (vector FP16 = 2x
// vector FP32 on CDNA) does 2 MACs per 2-cyc issue: 48 pk_fma replaces
// 48 dot2 at half the cycles. Accumulate in f16x2 with FOUR accumulators
// per gate (short chains, small partials -> f16 rounding ~2.4e-4/add);
// combine per gate with a pk_add tree + one dot2(s, {1,1}, base_f32).
//
// exp scale folding: r,z weights pre-scaled by -log2(e), n by +2*log2(e);
// activations use raw v_exp_f32 (2^x). Folding scales noise and slope
// together - no error amplification.

namespace {

typedef _Float16 f16x2 __attribute__((ext_vector_type(2)));

constexpr int kH = 32;
constexpr int kT = 512;
constexpr int kO = 12;
constexpr int kG = 8;  // batch elements (groups) per 256-thread block

__device__ __forceinline__ float fast_exp2(float a) {
#if __has_builtin(__builtin_amdgcn_exp2f)
    return __builtin_amdgcn_exp2f(a);
#else
    return exp2f(a);
#endif
}
__device__ __forceinline__ float fast_rcp(float a) {
#if __has_builtin(__builtin_amdgcn_rcpf)
    return __builtin_amdgcn_rcpf(a);
#else
    return 1.0f / a;
#endif
}

__device__ __forceinline__ float dot2(f16x2 a, f16x2 b, float c) {
#if __has_builtin(__builtin_amdgcn_fdot2)
    return __builtin_amdgcn_fdot2(a, b, c, false);
#else
    return fmaf((float)a[1], (float)b[1], fmaf((float)a[0], (float)b[0], c));
#endif
}

__device__ __forceinline__ f16x2 pkfma(f16x2 a, f16x2 b, f16x2 c) {
    return __builtin_elementwise_fma(a, b, c);
}

__device__ __forceinline__ f16x2 bc2(unsigned int u) {
    return __builtin_bit_cast(f16x2, u);
}

__global__ __launch_bounds__(256)
__attribute__((amdgpu_waves_per_eu(2, 2)))
void gru_fused(
    const float* __restrict__ x,      // [4096, 512, 1]
    const float* __restrict__ w_ih,   // [96, 1]
    const float* __restrict__ w_hh,   // [96, 32]
    const float* __restrict__ b_ih,   // [96]
    const float* __restrict__ b_hh,   // [96]
    const float* __restrict__ fc_w,   // [12, 32]
    const float* __restrict__ fc_b,   // [12]
    float* __restrict__ out)          // [4096, 12]
{
    __shared__ _Float16 hbuf[kG][kH];   // f16 h for the matvec
    __shared__ float    hfin[kG][kH];   // f32 final h for the FC epilogue

    const int tid = threadIdx.x;
    const int g   = tid >> 5;           // batch slot within block
    const int j   = tid & 31;           // hidden unit owned by this lane
    const int b   = blockIdx.x * kG + g;

    const float kL2E = 1.4426950408889634f;   // log2(e)

    // ---- per-lane weights: rows j (r), j+32 (z), j+64 (n), f16x2-packed,
    //      exp-scale folded: r,z by -log2e ; n by +2*log2e ----
    f16x2 wr[kH / 2], wz[kH / 2], wn[kH / 2];
    {
        const float* Wr = w_hh + (size_t)j * kH;
        const float* Wz = w_hh + (size_t)(j + kH) * kH;
        const float* Wn = w_hh + (size_t)(j + 2 * kH) * kH;
#pragma unroll
        for (int m = 0; m < kH / 2; ++m) {
            wr[m] = f16x2{(_Float16)(-kL2E * Wr[2 * m]),
                          (_Float16)(-kL2E * Wr[2 * m + 1])};
            wz[m] = f16x2{(_Float16)(-kL2E * Wz[2 * m]),
                          (_Float16)(-kL2E * Wz[2 * m + 1])};
            wn[m] = f16x2{(_Float16)(2.0f * kL2E * Wn[2 * m]),
                          (_Float16)(2.0f * kL2E * Wn[2 * m + 1])};
        }
    }

    // input-side constants (I == 1), same scale folding
    const float wih_r = -kL2E * w_ih[j];
    const float wih_z = -kL2E * w_ih[j + kH];
    const float wih_n = 2.0f * kL2E * w_ih[j + 2 * kH];
    const float bias_r = -kL2E * (b_ih[j] + b_hh[j]);
    const float bias_z = -kL2E * (b_ih[j + kH] + b_hh[j + kH]);
    const float bi_n = 2.0f * kL2E * b_ih[j + 2 * kH];
    const float bh_n = 2.0f * kL2E * b_hh[j + 2 * kH];

    const f16x2 kOnes = f16x2{(_Float16)1.0f, (_Float16)1.0f};

    float h = 0.0f;
    hbuf[g][j] = (_Float16)0.0f;  // same-wave write precedes all reads

    const float4* xrow4 = reinterpret_cast<const float4*>(x + (size_t)b * kT);
    const uint4*  hb4   = reinterpret_cast<const uint4*>(&hbuf[g][0]);

    float4 xv = xrow4[0];

    for (int t0 = 0; t0 < kT; t0 += 4) {
        const int nq = (t0 + 4 < kT) ? (t0 >> 2) + 1 : (t0 >> 2);
        float4 xnext = xrow4[nq];

#pragma unroll
        for (int tt = 0; tt < 4; ++tt) {
            const float xt = (tt == 0) ? xv.x : (tt == 1) ? xv.y
                           : (tt == 2) ? xv.z : xv.w;

            // h vector: 4x ds_read_b128 (same-address broadcast, no conflict)
            uint4 q0 = hb4[0], q1 = hb4[1], q2 = hb4[2], q3 = hb4[3];
            f16x2 hp[kH / 2];
            hp[0]  = bc2(q0.x); hp[1]  = bc2(q0.y);
            hp[2]  = bc2(q0.z); hp[3]  = bc2(q0.w);
            hp[4]  = bc2(q1.x); hp[5]  = bc2(q1.y);
            hp[6]  = bc2(q1.z); hp[7]  = bc2(q1.w);
            hp[8]  = bc2(q2.x); hp[9]  = bc2(q2.y);
            hp[10] = bc2(q2.z); hp[11] = bc2(q2.w);
            hp[12] = bc2(q3.x); hp[13] = bc2(q3.y);
            hp[14] = bc2(q3.z); hp[15] = bc2(q3.w);

            // ---- packed-f16 matvec, 4 accumulators per gate ----
            f16x2 aR[4], aZ[4], aN[4];
#pragma unroll
            for (int m = 0; m < 4; ++m) {
                aR[m] = wr[m] * hp[m];
                aZ[m] = wz[m] * hp[m];
                aN[m] = wn[m] * hp[m];
            }
#pragma unroll
            for (int m = 4; m < kH / 2; ++m) {
                const int s = m & 3;
                aR[s] = pkfma(wr[m], hp[m], aR[s]);
                aZ[s] = pkfma(wz[m], hp[m], aZ[s]);
                aN[s] = pkfma(wn[m], hp[m], aN[s]);
            }
            const f16x2 sR = (aR[0] + aR[1]) + (aR[2] + aR[3]);
            const f16x2 sZ = (aZ[0] + aZ[1]) + (aZ[2] + aZ[3]);
            const f16x2 sN = (aN[0] + aN[1]) + (aN[2] + aN[3]);

            // fold x-term + bias in f32, then add the two f16 halves via dot2
            const float ar = dot2(sR, kOnes, fmaf(xt, wih_r, bias_r));
            const float az = dot2(sZ, kOnes, fmaf(xt, wih_z, bias_z));
            const float an = dot2(sN, kOnes, bh_n);
            const float inn = fmaf(xt, wih_n, bi_n);

            // sigmoid(a) = 1/(1+2^(-log2e*a)) ; ar,az already scaled
            const float r = fast_rcp(1.0f + fast_exp2(ar));
            const float z = fast_rcp(1.0f + fast_exp2(az));
            // tanh(y) = 1 - 2/(2^(2log2e*y)+1) ; inn,an already scaled
            const float targ = fmaf(r, an, inn);
            const float n = fmaf(-2.0f, fast_rcp(1.0f + fast_exp2(targ)), 1.0f);
            h = fmaf(z, h - n, n);                // (1-z)*n + z*h

            hbuf[g][j] = (_Float16)h;             // publish for next step
        }
        xv = xnext;
    }

    // ---- FC epilogue: out[b][o] = fc_w[o] . h + fc_b[o] ----
    hfin[g][j] = h;
    if (j < kO) {
        float acc = fc_b[j];
        const float* fw = fc_w + (size_t)j * kH;
#pragma unroll
        for (int k = 0; k < kH; ++k)
            acc = fmaf(fw[k], hfin[g][k], acc);
        out[(size_t)b * kO + j] = acc;
    }
}

}  // namespace

extern "C" void kernel_launch(void* const* d_in, const int* in_sizes, int n_in,
                              void* d_out, int out_size, void* d_ws, size_t ws_size,
                              hipStream_t stream) {
    const float* x    = (const float*)d_in[0];
    const float* w_ih = (const float*)d_in[1];
    const float* w_hh = (const float*)d_in[2];
    const float* b_ih = (const float*)d_in[3];
    const float* b_hh = (const float*)d_in[4];
    const float* fc_w = (const float*)d_in[5];
    const float* fc_b = (const float*)d_in[6];
    float* out = (float*)d_out;

    dim3 grid(4096 / kG);   // 512 blocks, 4 waves each -> 2048 waves
    dim3 block(256);
    gru_fused<<<grid, block, 0, stream>>>(x, w_ih, w_hh, b_ih, b_hh, fc_w, fc_b, out);
}